// Round 2
// baseline (226.518 us; speedup 1.0000x reference)
//
#include <hip/hip_runtime.h>
#include <hip/hip_bf16.h>
#include <stdint.h>

typedef __bf16 bf16x8 __attribute__((ext_vector_type(8)));
typedef float floatx4 __attribute__((ext_vector_type(4)));

#define B_ 2
#define L_ 4096
#define C_ 1024
#define H_ 16
#define D_ 64
constexpr size_t TEN = (size_t)B_ * H_ * L_ * D_;  // 8388608 elems per q/k/v tensor

__device__ __forceinline__ float bf2f(unsigned short u) {
  union { unsigned int i; float f; } x; x.i = ((unsigned int)u) << 16; return x.f;
}
__device__ __forceinline__ unsigned short f2bf(float f) {
  union { float f; unsigned int i; } x; x.f = f;
  unsigned int i = x.i;
  return (unsigned short)((i + 0x7FFFu + ((i >> 16) & 1u)) >> 16);
}

// ---------------- elementwise f32 -> bf16 ----------------
__global__ __launch_bounds__(256) void cvt_f32_bf16_kernel(
    const float* __restrict__ in, unsigned short* __restrict__ out, int n) {
  int i = (blockIdx.x * 256 + threadIdx.x) * 8;
  if (i >= n) return;
  float4 a = *(const float4*)&in[i];
  float4 b = *(const float4*)&in[i + 4];
  union { uint4 u; unsigned short s[8]; } st;
  st.s[0] = f2bf(a.x); st.s[1] = f2bf(a.y); st.s[2] = f2bf(a.z); st.s[3] = f2bf(a.w);
  st.s[4] = f2bf(b.x); st.s[5] = f2bf(b.y); st.s[6] = f2bf(b.z); st.s[7] = f2bf(b.w);
  *(uint4*)&out[i] = st.u;
}

// ---------------- transpose f32 in -> bf16 out, dims divisible by 64 ----------------
// in: R x Ccols (f32); out: Ccols x R (bf16)
__global__ __launch_bounds__(256) void transpose_f32_bf16(
    const float* __restrict__ in, unsigned short* __restrict__ out,
    int R, int Ccols) {
  __shared__ float tile[64][65];
  const int bx = blockIdx.x * 64;  // col base in input
  const int by = blockIdx.y * 64;  // row base in input
  const int t = threadIdx.x;
  for (int i = t; i < 1024; i += 256) {
    int r = i >> 4, c4 = (i & 15) << 2;
    float4 v = *(const float4*)&in[(size_t)(by + r) * Ccols + bx + c4];
    tile[r][c4] = v.x; tile[r][c4 + 1] = v.y; tile[r][c4 + 2] = v.z; tile[r][c4 + 3] = v.w;
  }
  __syncthreads();
  for (int i = t; i < 512; i += 256) {
    int r = i >> 3, c8 = (i & 7) << 3;  // r = output row (input col)
    union { uint4 u; unsigned short s[8]; } st;
    #pragma unroll
    for (int j = 0; j < 8; ++j) st.s[j] = f2bf(tile[c8 + j][r]);
    *(uint4*)&out[(size_t)(bx + r) * R + by + c8] = st.u;
  }
}

// ---------------- GEMM: A (MxK, bf16) * Bt^T (Bt is NxK, bf16), MFMA ----------------
// MODE 0: scatter into q/k/v (B,H,L,D) bf16 with bias + q-scale
// MODE 1: plain C = A*B + bias -> out_f (MxN f32)
template <int MODE>
__global__ __launch_bounds__(256) void gemm_bt_kernel(
    const unsigned short* __restrict__ A, const unsigned short* __restrict__ Bt,
    const float* __restrict__ bias, unsigned short* __restrict__ out_bf,
    float* __restrict__ out_f, int M, int N, int K, float qscale) {
  constexpr int BK = 64;
  constexpr int LDA = 72;  // padded row (bf16 elems): 2-way LDS aliasing only (free)
  __shared__ unsigned short a_sh[128 * LDA];
  __shared__ unsigned short b_sh[128 * LDA];

  const int t = threadIdx.x;
  const int m0 = blockIdx.y * 128;
  const int n0 = blockIdx.x * 128;
  const int wave = t >> 6, lane = t & 63;
  const int wr = wave >> 1, wc = wave & 1;
  const int lm = lane & 15, quad = lane >> 4;

  floatx4 acc[4][4];
  #pragma unroll
  for (int i = 0; i < 4; ++i)
    #pragma unroll
    for (int j = 0; j < 4; ++j) acc[i][j] = (floatx4)0.0f;

  for (int kt = 0; kt < K; kt += BK) {
    #pragma unroll
    for (int p = 0; p < 4; ++p) {
      int idx = (p * 256 + t) * 8;
      int r = idx >> 6, c = idx & 63;
      uint4 va = *(const uint4*)&A[(size_t)(m0 + r) * K + kt + c];
      *(uint4*)&a_sh[r * LDA + c] = va;
      uint4 vb = *(const uint4*)&Bt[(size_t)(n0 + r) * K + kt + c];
      *(uint4*)&b_sh[r * LDA + c] = vb;
    }
    __syncthreads();
    #pragma unroll
    for (int ks = 0; ks < BK; ks += 32) {
      bf16x8 af[4], bfr[4];
      #pragma unroll
      for (int i = 0; i < 4; ++i)
        af[i] = *(const bf16x8*)&a_sh[(wr * 64 + i * 16 + lm) * LDA + ks + quad * 8];
      #pragma unroll
      for (int j = 0; j < 4; ++j)
        bfr[j] = *(const bf16x8*)&b_sh[(wc * 64 + j * 16 + lm) * LDA + ks + quad * 8];
      #pragma unroll
      for (int i = 0; i < 4; ++i)
        #pragma unroll
        for (int j = 0; j < 4; ++j)
          acc[i][j] = __builtin_amdgcn_mfma_f32_16x16x32_bf16(af[i], bfr[j], acc[i][j], 0, 0, 0);
    }
    __syncthreads();
  }

  #pragma unroll
  for (int j = 0; j < 4; ++j) {
    int col = n0 + wc * 64 + j * 16 + lm;
    float bv = bias[col];
    if (MODE == 0) {
      int which = col >> 10;
      int rem = col & 1023;
      int h = rem >> 6, d = rem & 63;
      float mul = (which == 0) ? qscale : 1.0f;
      #pragma unroll
      for (int i = 0; i < 4; ++i)
        #pragma unroll
        for (int r = 0; r < 4; ++r) {
          int row = m0 + wr * 64 + i * 16 + quad * 4 + r;
          int b = row >> 12, l = row & (L_ - 1);
          float v = (acc[i][j][r] + bv) * mul;
          out_bf[(size_t)which * TEN + (((size_t)(b * H_ + h) * L_ + l) * D_ + d)] = f2bf(v);
        }
    } else {
      #pragma unroll
      for (int i = 0; i < 4; ++i)
        #pragma unroll
        for (int r = 0; r < 4; ++r) {
          int row = m0 + wr * 64 + i * 16 + quad * 4 + r;
          out_f[(size_t)row * N + col] = acc[i][j][r] + bv;
        }
    }
  }
}

// ---------------- neighborhood attention, online softmax ----------------
constexpr int KKMAX = 63;
constexpr int TL = 128;
constexpr int LDK = 72;

__global__ __launch_bounds__(256) void natt_kernel(
    const unsigned short* __restrict__ qkv,  // q,k,v each TEN elems, (B,H,L,D) bf16
    const float* __restrict__ rpb,           // H x (2kk-1) f32
    const int* __restrict__ knp,
    unsigned short* __restrict__ attn_out) {  // (B*L) x C bf16
  __shared__ unsigned short k_sh[(TL + KKMAX) * LDK];
  __shared__ unsigned short v_sh[(TL + KKMAX) * LDK];
  __shared__ float rpb_sh[2 * KKMAX + 1];

  const int bh = blockIdx.x;
  const int h = bh & (H_ - 1);
  const int b = bh >> 4;
  const int l0 = blockIdx.y * TL;
  const int t = threadIdx.x;

  int kn = knp[0];
  if (kn > 65536 || kn < 0) {  // guard: value stored as float bits
    union { int i; float f; } u; u.i = kn; kn = (int)u.f;
  }
  int rr = 1;
  while ((rr + 1) * (rr + 1) <= kn) ++rr;
  int kk = rr + 1;
  if (kk > KKMAX) kk = KKMAX;

  int base = l0 - kk / 2;
  if (base < 0) base = 0;
  if (base > L_ - kk) base = L_ - kk;
  int nrows = TL + kk;
  if (nrows > L_ - base) nrows = L_ - base;

  const unsigned short* kg = qkv + TEN + (size_t)bh * L_ * D_;
  const unsigned short* vg = qkv + 2 * TEN + (size_t)bh * L_ * D_;

  for (int i = t; i < nrows * 8; i += 256) {
    int row = i >> 3, c8 = (i & 7) << 3;
    uint4 kv = *(const uint4*)&kg[(size_t)(base + row) * D_ + c8];
    *(uint4*)&k_sh[row * LDK + c8] = kv;
    uint4 vv = *(const uint4*)&vg[(size_t)(base + row) * D_ + c8];
    *(uint4*)&v_sh[row * LDK + c8] = vv;
  }
  int nb = 2 * kk - 1;
  for (int i = t; i < nb; i += 256) rpb_sh[i] = rpb[h * nb + i];
  __syncthreads();

  const int qi = t >> 1, half = t & 1;
  const int l = l0 + qi;

  const unsigned short* qg = qkv + (size_t)bh * L_ * D_ + (size_t)l * D_ + half * 32;
  float qv[32];
  #pragma unroll
  for (int c = 0; c < 4; ++c) {
    union { uint4 u; unsigned short s[8]; } ld;
    ld.u = *(const uint4*)&qg[c * 8];
    #pragma unroll
    for (int j = 0; j < 8; ++j) qv[c * 8 + j] = bf2f(ld.s[j]);
  }

  int start = l - kk / 2;
  if (start < 0) start = 0;
  if (start > L_ - kk) start = L_ - kk;
  const int srow = start - base;
  const int boff = start - l + kk - 1;

  float m = -1e30f, lsum = 0.0f;
  float accv[32];
  #pragma unroll
  for (int d = 0; d < 32; ++d) accv[d] = 0.0f;

  for (int j = 0; j < kk; ++j) {
    const unsigned short* kr = &k_sh[(srow + j) * LDK + half * 32];
    float partial = 0.0f;
    #pragma unroll
    for (int c = 0; c < 4; ++c) {
      union { uint4 u; unsigned short s[8]; } ld;
      ld.u = *(const uint4*)&kr[c * 8];
      #pragma unroll
      for (int jj = 0; jj < 8; ++jj) partial += qv[c * 8 + jj] * bf2f(ld.s[jj]);
    }
    float s = partial + __shfl_xor(partial, 1) + rpb_sh[boff + j];
    float p;
    if (s > m) {
      float corr = __expf(m - s);
      lsum *= corr;
      #pragma unroll
      for (int d = 0; d < 32; ++d) accv[d] *= corr;
      m = s;
      p = 1.0f;
    } else {
      p = __expf(s - m);
    }
    lsum += p;
    const unsigned short* vr = &v_sh[(srow + j) * LDK + half * 32];
    #pragma unroll
    for (int c = 0; c < 4; ++c) {
      union { uint4 u; unsigned short s[8]; } ld;
      ld.u = *(const uint4*)&vr[c * 8];
      #pragma unroll
      for (int jj = 0; jj < 8; ++jj) accv[c * 8 + jj] += p * bf2f(ld.s[jj]);
    }
  }
  float inv = 1.0f / lsum;
  unsigned short* og = attn_out + ((size_t)(b * L_ + l) * C_ + h * D_ + half * 32);
  #pragma unroll
  for (int c = 0; c < 4; ++c) {
    union { uint4 u; unsigned short s[8]; } st;
    #pragma unroll
    for (int jj = 0; jj < 8; ++jj) st.s[jj] = f2bf(accv[c * 8 + jj] * inv);
    *(uint4*)&og[c * 8] = st.u;
  }
}

extern "C" void kernel_launch(void* const* d_in, const int* in_sizes, int n_in,
                              void* d_out, int out_size, void* d_ws, size_t ws_size,
                              hipStream_t stream) {
  const float* x      = (const float*)d_in[0];
  const float* w_qkv  = (const float*)d_in[1];
  const float* b_qkv  = (const float*)d_in[2];
  const float* rpb    = (const float*)d_in[3];
  const float* w_proj = (const float*)d_in[4];
  const float* b_proj = (const float*)d_in[5];
  const int* kn       = (const int*)d_in[6];
  float* out          = (float*)d_out;

  unsigned short* ws      = (unsigned short*)d_ws;
  unsigned short* wT_qkv  = ws;                              // 3072x1024 bf16
  unsigned short* wT_proj = wT_qkv + (size_t)3072 * 1024;    // 1024x1024 bf16
  unsigned short* x_bf    = wT_proj + (size_t)1024 * 1024;   // 8192x1024 bf16
  unsigned short* qkv_ws  = x_bf + (size_t)8192 * 1024;      // 3*TEN bf16
  unsigned short* attn_ws = qkv_ws + 3 * TEN;                // 8192x1024 bf16

  cvt_f32_bf16_kernel<<<(8192 * 1024) / (256 * 8), 256, 0, stream>>>(x, x_bf, 8192 * 1024);
  transpose_f32_bf16<<<dim3(3072 / 64, 1024 / 64), 256, 0, stream>>>(w_qkv, wT_qkv, 1024, 3072);
  transpose_f32_bf16<<<dim3(1024 / 64, 1024 / 64), 256, 0, stream>>>(w_proj, wT_proj, 1024, 1024);
  gemm_bt_kernel<0><<<dim3(3072 / 128, 8192 / 128), 256, 0, stream>>>(
      x_bf, wT_qkv, b_qkv, qkv_ws, nullptr, 8192, 3072, 1024, 0.125f);
  natt_kernel<<<dim3(B_ * H_, L_ / TL), 256, 0, stream>>>(qkv_ws, rpb, kn, attn_ws);
  gemm_bt_kernel<1><<<dim3(1024 / 128, 8192 / 128), 256, 0, stream>>>(
      attn_ws, wT_proj, b_proj, nullptr, out, 8192, 1024, 1024, 1.0f);
}